// Round 2
// baseline (5142.584 us; speedup 1.0000x reference)
//
#include <hip/hip_runtime.h>

#define USH unsigned short

// ---------- bf16 helpers (bit-exact, no __bf16 arithmetic) ----------
__device__ __forceinline__ float bf2f(USH u) {
    return __uint_as_float(((unsigned int)u) << 16);
}
__device__ __forceinline__ float bfbits2f(unsigned int b) {
    return __uint_as_float(b << 16);
}
__device__ __forceinline__ USH f2bf(float f) {
    unsigned int x = __float_as_uint(f);
    x += 0x7fffu + ((x >> 16) & 1u);   // RNE
    return (USH)(x >> 16);
}
__device__ __forceinline__ unsigned int pack2bf(float a, float b) {
    return (unsigned int)f2bf(a) | ((unsigned int)f2bf(b) << 16);
}
__device__ __forceinline__ float sigmoidf_(float x) { return 1.0f / (1.0f + expf(-x)); }

typedef __bf16 bf16x8 __attribute__((ext_vector_type(8)));
typedef float floatx4 __attribute__((ext_vector_type(4)));

// ---------------------------------------------------------------
// BT-GEMM: C[m,n] = epi( sum_k A[m,k] * W[n,k] + bias[n] )
// A is bf16. W is fp32 (WF32=true, converted during staging) or bf16.
// 128x128 tile, BK=32, 4 waves (2x2 of 64x64), 16x16x32 bf16 MFMA.
// A-frag: lane holds A[m=lane&15][k=(lane>>4)*8+j]; W-frag same with n.
// C/D: col=lane&15, row=(lane>>4)*4+reg   [measured m89/m91]
// LDS row stride 40 bf16 (80B).
// ---------------------------------------------------------------
enum { EPI_SCORES = 0, EPI_GELU = 1, EPI_GATE = 2, EPI_PLAIN = 3 };

template <int EPI, bool WF32>
__global__ __launch_bounds__(256)
void gemm_bt(const USH* __restrict__ A, int lda, long long sAz,
             const void* __restrict__ Wv, int ldw, long long sWz,
             void* __restrict__ Cout, int ldc, long long sCz,
             const float* __restrict__ bias, const float* __restrict__ fmul,
             float alpha, int Kd)
{
    __shared__ USH As[128 * 40];
    __shared__ USH Ws[128 * 40];
    const int z = blockIdx.z;
    A += (size_t)z * (size_t)sAz;
    const USH* Wb = (const USH*)Wv;
    const float* Wf = (const float*)Wv;
    Wb += (size_t)z * (size_t)sWz;
    Wf += (size_t)z * (size_t)sWz;
    const int m0 = blockIdx.y * 128;
    const int n0 = blockIdx.x * 128;
    const int tid = threadIdx.x;
    const int lane = tid & 63;
    const int wid = tid >> 6;
    const int wm = (wid >> 1) * 64;
    const int wn = (wid & 1) * 64;
    const int q = lane >> 4;
    const int r = lane & 15;
    const int srow = tid >> 1;
    const int scol = (tid & 1) * 16;

    floatx4 acc[4][4] = {};

    const USH* ap = A + (size_t)(m0 + srow) * lda + scol;
    USH* asw = &As[srow * 40 + scol];
    USH* wsw = &Ws[srow * 40 + scol];

    const USH* wpb = Wb + (size_t)(n0 + srow) * ldw + scol;
    const float* wpf = Wf + (size_t)(n0 + srow) * ldw + scol;

    for (int k0 = 0; k0 < Kd; k0 += 32) {
        uint4 a0 = *reinterpret_cast<const uint4*>(ap + k0);
        uint4 a1 = *reinterpret_cast<const uint4*>(ap + k0 + 8);
        uint4 w0, w1;
        if (WF32) {
            float4 f0 = *reinterpret_cast<const float4*>(wpf + k0);
            float4 f1 = *reinterpret_cast<const float4*>(wpf + k0 + 4);
            float4 f2 = *reinterpret_cast<const float4*>(wpf + k0 + 8);
            float4 f3 = *reinterpret_cast<const float4*>(wpf + k0 + 12);
            w0.x = pack2bf(f0.x, f0.y); w0.y = pack2bf(f0.z, f0.w);
            w0.z = pack2bf(f1.x, f1.y); w0.w = pack2bf(f1.z, f1.w);
            w1.x = pack2bf(f2.x, f2.y); w1.y = pack2bf(f2.z, f2.w);
            w1.z = pack2bf(f3.x, f3.y); w1.w = pack2bf(f3.z, f3.w);
        } else {
            w0 = *reinterpret_cast<const uint4*>(wpb + k0);
            w1 = *reinterpret_cast<const uint4*>(wpb + k0 + 8);
        }
        *reinterpret_cast<uint4*>(asw) = a0;
        *reinterpret_cast<uint4*>(asw + 8) = a1;
        *reinterpret_cast<uint4*>(wsw) = w0;
        *reinterpret_cast<uint4*>(wsw + 8) = w1;
        __syncthreads();
        bf16x8 af[4], wf[4];
#pragma unroll
        for (int i = 0; i < 4; i++)
            af[i] = *reinterpret_cast<const bf16x8*>(&As[(wm + i * 16 + r) * 40 + q * 8]);
#pragma unroll
        for (int j = 0; j < 4; j++)
            wf[j] = *reinterpret_cast<const bf16x8*>(&Ws[(wn + j * 16 + r) * 40 + q * 8]);
#pragma unroll
        for (int i = 0; i < 4; i++)
#pragma unroll
            for (int j = 0; j < 4; j++)
                acc[i][j] = __builtin_amdgcn_mfma_f32_16x16x32_bf16(af[i], wf[j], acc[i][j], 0, 0, 0);
        __syncthreads();
    }

#pragma unroll
    for (int j = 0; j < 4; j++) {
        const int col = n0 + wn + j * 16 + r;
        const float bv = (EPI == EPI_SCORES) ? 0.f : bias[col];
#pragma unroll
        for (int i = 0; i < 4; i++) {
            const int row0 = m0 + wm + i * 16 + q * 4;
#pragma unroll
            for (int rr = 0; rr < 4; rr++) {
                const int row = row0 + rr;
                float v = acc[i][j][rr];
                if (EPI == EPI_SCORES) {
                    ((float*)Cout)[(size_t)z * (size_t)sCz + (size_t)row * ldc + col] = v * alpha;
                } else if (EPI == EPI_GELU) {
                    v += bv;
                    float g = 0.5f * v * (1.0f + erff(v * 0.7071067811865475f));
                    ((USH*)Cout)[(size_t)row * ldc + col] = f2bf(g);
                } else if (EPI == EPI_GATE) {
                    v += bv;
                    float gate = 1.0f / (1.0f + expf(-v));
                    float o = gate * fmul[(size_t)row * ldc + col];
                    ((USH*)Cout)[(size_t)row * ldc + col] = f2bf(o);
                } else {
                    ((USH*)Cout)[(size_t)row * ldc + col] = f2bf(v + bv);
                }
            }
        }
    }
}

// ---------------------------------------------------------------
// means: z<24 -> y[z][d] = mean_n feats[z,n,d]; z==24 -> tg[d] = mean_t text
// z==25 -> zero cell state (replaces hipMemsetAsync)
// ---------------------------------------------------------------
__global__ __launch_bounds__(256)
void means_k(const float* __restrict__ text, const float* __restrict__ feats,
             float* __restrict__ tg, float* __restrict__ yv, float* __restrict__ cst)
{
    const int d = blockIdx.x * 256 + threadIdx.x;
    const int z = blockIdx.y;
    if (z < 24) {
        const float* f = feats + (size_t)z * 576 * 4096 + d;
        float s = 0.f;
        for (int n = 0; n < 576; n++) s += f[(size_t)n * 4096];
        yv[z * 4096 + d] = s * (1.0f / 576.0f);
    } else if (z == 24) {
        float s = 0.f;
        for (int t = 0; t < 128; t++) s += text[(size_t)t * 4096 + d];
        tg[d] = s * (1.0f / 128.0f);
    } else {
        cst[d] = 0.f;
    }
}

// ---------------------------------------------------------------
// text -> bf16 copy (for Q gemm A-operand)
// ---------------------------------------------------------------
__global__ __launch_bounds__(256)
void f32_to_bf16(const float* __restrict__ src, USH* __restrict__ dst)
{
    const size_t base = ((size_t)blockIdx.x * 256 + threadIdx.x) * 8;
    float4 f0 = *reinterpret_cast<const float4*>(src + base);
    float4 f1 = *reinterpret_cast<const float4*>(src + base + 4);
    uint4 ov;
    ov.x = pack2bf(f0.x, f0.y); ov.y = pack2bf(f0.z, f0.w);
    ov.z = pack2bf(f1.x, f1.y); ov.w = pack2bf(f1.z, f1.w);
    *reinterpret_cast<uint4*>(dst + base) = ov;
}

// ---------------------------------------------------------------
// DSU step 1: s[r] = relu( W1[r,:] . [sigmoid(c), y_l, tg] + W1_b[r] )
// ---------------------------------------------------------------
__global__ __launch_bounds__(256)
void dsu_s1(const float* __restrict__ W1w, const float* __restrict__ W1b,
            const float* __restrict__ c, const float* __restrict__ yl,
            const float* __restrict__ tg, float* __restrict__ sv)
{
    const int rrow = blockIdx.x;
    const float* w = W1w + (size_t)rrow * 12288;
    const int tid = threadIdx.x;
    float acc = 0.f;
    for (int k = tid; k < 4096; k += 256) acc += w[k] * sigmoidf_(c[k]);
    for (int k = tid; k < 4096; k += 256) acc += w[4096 + k] * yl[k];
    for (int k = tid; k < 4096; k += 256) acc += w[8192 + k] * tg[k];
#pragma unroll
    for (int o = 32; o > 0; o >>= 1) acc += __shfl_down(acc, o, 64);
    __shared__ float red[4];
    if ((tid & 63) == 0) red[tid >> 6] = acc;
    __syncthreads();
    if (tid == 0) {
        float t = red[0] + red[1] + red[2] + red[3] + W1b[rrow];
        sv[rrow] = fmaxf(t, 0.f);
    }
}

// ---------------------------------------------------------------
// DSU step 2: gates + cell update + ctx write
// ---------------------------------------------------------------
__global__ __launch_bounds__(256)
void dsu_s2(const float* __restrict__ Wc, const float* __restrict__ Wcb,
            const float* __restrict__ Wi, const float* __restrict__ Wib,
            const float* __restrict__ Wf, const float* __restrict__ Wfb,
            const float* __restrict__ bc, const float* __restrict__ bi,
            const float* __restrict__ bfv,
            const float* __restrict__ sv, float* __restrict__ c,
            float* __restrict__ ctx_l)
{
    const int d = blockIdx.x;
    const int tid = threadIdx.x;
    float a0 = 0.f, a1 = 0.f, a2 = 0.f;
    for (int k = tid; k < 1024; k += 256) {
        float s = sv[k];
        a0 += Wc[(size_t)d * 1024 + k] * s;
        a1 += Wi[(size_t)d * 1024 + k] * s;
        a2 += Wf[(size_t)d * 1024 + k] * s;
    }
#pragma unroll
    for (int o = 32; o > 0; o >>= 1) {
        a0 += __shfl_down(a0, o, 64);
        a1 += __shfl_down(a1, o, 64);
        a2 += __shfl_down(a2, o, 64);
    }
    __shared__ float red[3][4];
    if ((tid & 63) == 0) {
        red[0][tid >> 6] = a0; red[1][tid >> 6] = a1; red[2][tid >> 6] = a2;
    }
    __syncthreads();
    if (tid == 0) {
        float A0 = red[0][0] + red[0][1] + red[0][2] + red[0][3];
        float A1 = red[1][0] + red[1][1] + red[1][2] + red[1][3];
        float A2 = red[2][0] + red[2][1] + red[2][2] + red[2][3];
        float ct = tanhf(A0 + Wcb[d] + bc[d]);
        float ig = sigmoidf_(A1 + Wib[d] + bi[d]);
        float fg = sigmoidf_(A2 + Wfb[d] + bfv[d]);
        float cn = fg * c[d] + ig * ct;
        c[d] = cn;
        ctx_l[d] = cn;
    }
}

// ---------------------------------------------------------------
// X = bf16( feats + ctx[layer] )   (8 elements/thread); feats fp32
// ---------------------------------------------------------------
__global__ __launch_bounds__(256)
void make_x(const float* __restrict__ feats, const float* __restrict__ ctx,
            USH* __restrict__ X)
{
    const size_t base = ((size_t)blockIdx.x * 256 + threadIdx.x) * 8;
    const int row = (int)(base >> 12);
    const int l = row / 576;
    const float* cr = ctx + (size_t)l * 4096 + (base & 4095);
    float4 f0 = *reinterpret_cast<const float4*>(feats + base);
    float4 f1 = *reinterpret_cast<const float4*>(feats + base + 4);
    uint4 ov;
    ov.x = pack2bf(f0.x + cr[0], f0.y + cr[1]);
    ov.y = pack2bf(f0.z + cr[2], f0.w + cr[3]);
    ov.z = pack2bf(f1.x + cr[4], f1.y + cr[5]);
    ov.w = pack2bf(f1.z + cr[6], f1.w + cr[7]);
    *reinterpret_cast<uint4*>(X + base) = ov;
}

// ---------------------------------------------------------------
// LayerNorm over rows of width 4096; in bf16, gamma/beta fp32,
// out bf16 (OUTF32=false) or fp32 (OUTF32=true)
// ---------------------------------------------------------------
template <bool OUTF32>
__global__ __launch_bounds__(256)
void ln_rows(const USH* __restrict__ in, void* __restrict__ out,
             const float* __restrict__ g, const float* __restrict__ b)
{
    const int row = blockIdx.x;
    const USH* x = in + (size_t)row * 4096;
    const int tid = threadIdx.x;
    float vals[16];
    float s = 0.f, ss = 0.f;
#pragma unroll
    for (int i = 0; i < 16; i++) {
        float v = bf2f(x[tid + i * 256]);
        vals[i] = v; s += v; ss += v * v;
    }
#pragma unroll
    for (int off = 32; off > 0; off >>= 1) {
        s += __shfl_down(s, off, 64);
        ss += __shfl_down(ss, off, 64);
    }
    __shared__ float rs[4], rss[4];
    __shared__ float stats[2];
    if ((tid & 63) == 0) { rs[tid >> 6] = s; rss[tid >> 6] = ss; }
    __syncthreads();
    if (tid == 0) {
        float S = rs[0] + rs[1] + rs[2] + rs[3];
        float SS = rss[0] + rss[1] + rss[2] + rss[3];
        float mean = S * (1.0f / 4096.0f);
        float var = SS * (1.0f / 4096.0f) - mean * mean;
        stats[0] = mean;
        stats[1] = rsqrtf(var + 1e-5f);
    }
    __syncthreads();
    const float mean = stats[0], rstd = stats[1];
#pragma unroll
    for (int i = 0; i < 16; i++) {
        const int cidx = tid + i * 256;
        float v = (vals[i] - mean) * rstd * g[cidx] + b[cidx];
        if (OUTF32) ((float*)out)[(size_t)row * 4096 + cidx] = v;
        else ((USH*)out)[(size_t)row * 4096 + cidx] = f2bf(v);
    }
}

// ---------------------------------------------------------------
// softmax over 13824 per row (scores fp32 -> probs bf16)
// ---------------------------------------------------------------
__global__ __launch_bounds__(256)
void softmax_rows(const float* __restrict__ scores, USH* __restrict__ probs)
{
    const int row = blockIdx.x;   // h*128 + t
    const float* x = scores + (size_t)row * 13824;
    USH* p = probs + (size_t)row * 13824;
    const int tid = threadIdx.x;
    float mx = -1e30f;
    for (int i = tid; i < 13824; i += 256) mx = fmaxf(mx, x[i]);
#pragma unroll
    for (int off = 32; off > 0; off >>= 1) mx = fmaxf(mx, __shfl_down(mx, off, 64));
    __shared__ float rm[4];
    __shared__ float bm, bs;
    if ((tid & 63) == 0) rm[tid >> 6] = mx;
    __syncthreads();
    if (tid == 0) bm = fmaxf(fmaxf(rm[0], rm[1]), fmaxf(rm[2], rm[3]));
    __syncthreads();
    const float M = bm;
    float sum = 0.f;
    for (int i = tid; i < 13824; i += 256) sum += expf(x[i] - M);
#pragma unroll
    for (int off = 32; off > 0; off >>= 1) sum += __shfl_down(sum, off, 64);
    if ((tid & 63) == 0) rm[tid >> 6] = sum;
    __syncthreads();
    if (tid == 0) bs = 1.0f / (rm[0] + rm[1] + rm[2] + rm[3]);
    __syncthreads();
    const float inv = bs;
    for (int i = tid; i < 13824; i += 256) p[i] = f2bf(expf(x[i] - M) * inv);
}

// ---------------------------------------------------------------
// PV: att[t, h*512+d] = sum_s P[h,t,s] * V[s, h*512+d]
// grid (dchunk=8, tchunk=4, head=8); block: 32 t x 8 d-groups of 8
// ---------------------------------------------------------------
__global__ __launch_bounds__(256)
void pv_kernel(const USH* __restrict__ P, const USH* __restrict__ V,
               USH* __restrict__ att)
{
    const int h = blockIdx.z;
    const int d0 = blockIdx.x * 64;
    const int t0 = blockIdx.y * 32;
    const int tid = threadIdx.x;
    const int tl = tid >> 3;    // 0..31
    const int dg = tid & 7;     // d = d0 + dg*8 .. +8
    __shared__ USH Ps[32][72];
    __shared__ USH Vs[64][72];
    float acc[8] = {0.f, 0.f, 0.f, 0.f, 0.f, 0.f, 0.f, 0.f};

    for (int sc = 0; sc < 13824; sc += 64) {
        {
            const USH* pp = P + (size_t)(h * 128 + t0 + (tid >> 3)) * 13824 + sc + (tid & 7) * 8;
            uint4 v = *reinterpret_cast<const uint4*>(pp);
            *reinterpret_cast<uint4*>(&Ps[tid >> 3][(tid & 7) * 8]) = v;
        }
        {
            const USH* vp = V + (size_t)(sc + (tid >> 2)) * 4096 + h * 512 + d0 + (tid & 3) * 16;
            uint4 v0 = *reinterpret_cast<const uint4*>(vp);
            uint4 v1 = *reinterpret_cast<const uint4*>(vp + 8);
            *reinterpret_cast<uint4*>(&Vs[tid >> 2][(tid & 3) * 16]) = v0;
            *reinterpret_cast<uint4*>(&Vs[tid >> 2][(tid & 3) * 16 + 8]) = v1;
        }
        __syncthreads();
#pragma unroll 8
        for (int s8 = 0; s8 < 64; s8++) {
            float pv = bf2f(Ps[tl][s8]);
            uint4 raw = *reinterpret_cast<const uint4*>(&Vs[s8][dg * 8]);
            acc[0] += pv * bfbits2f(raw.x & 0xffffu);
            acc[1] += pv * bfbits2f(raw.x >> 16);
            acc[2] += pv * bfbits2f(raw.y & 0xffffu);
            acc[3] += pv * bfbits2f(raw.y >> 16);
            acc[4] += pv * bfbits2f(raw.z & 0xffffu);
            acc[5] += pv * bfbits2f(raw.z >> 16);
            acc[6] += pv * bfbits2f(raw.w & 0xffffu);
            acc[7] += pv * bfbits2f(raw.w >> 16);
        }
        __syncthreads();
    }
    USH* o = att + (size_t)(t0 + tl) * 4096 + h * 512 + d0 + dg * 8;
    uint4 ov;
    ov.x = pack2bf(acc[0], acc[1]);
    ov.y = pack2bf(acc[2], acc[3]);
    ov.z = pack2bf(acc[4], acc[5]);
    ov.w = pack2bf(acc[6], acc[7]);
    *reinterpret_cast<uint4*>(o) = ov;
}

// ---------------------------------------------------------------
extern "C" void kernel_launch(void* const* d_in, const int* in_sizes, int n_in,
                              void* d_out, int out_size, void* d_ws, size_t ws_size,
                              hipStream_t stream)
{
    const float* text = (const float*)d_in[0];
    const float* feats = (const float*)d_in[1];
    const float* W1w = (const float*)d_in[2];
    const float* W1b = (const float*)d_in[3];
    const float* Wcw = (const float*)d_in[4];
    const float* Wcb = (const float*)d_in[5];
    const float* Wiw = (const float*)d_in[6];
    const float* Wib = (const float*)d_in[7];
    const float* Wfw = (const float*)d_in[8];
    const float* Wfb = (const float*)d_in[9];
    const float* bc  = (const float*)d_in[10];
    const float* bi  = (const float*)d_in[11];
    const float* bfv = (const float*)d_in[12];
    const float* g1w = (const float*)d_in[13];
    const float* g1b = (const float*)d_in[14];
    const float* g2w = (const float*)d_in[15];
    const float* g2b = (const float*)d_in[16];
    const float* Wqw = (const float*)d_in[17];
    const float* Wqb = (const float*)d_in[18];
    const float* Wkw = (const float*)d_in[19];
    const float* Wkb = (const float*)d_in[20];
    const float* Wow = (const float*)d_in[21];
    const float* Wob = (const float*)d_in[22];
    const float* qng = (const float*)d_in[23];
    const float* qnb = (const float*)d_in[24];
    const float* kng = (const float*)d_in[25];
    const float* knb = (const float*)d_in[26];
    const float* ong = (const float*)d_in[27];
    const float* onb = (const float*)d_in[28];

    // ---- workspace layout (bump allocator, 256B aligned) ----
    char* base = (char*)d_ws;
    size_t off = 0;
    auto take = [&](size_t nbytes) -> char* {
        char* p = base + off;
        off += (nbytes + 255) & ~(size_t)255;
        return p;
    };
    const size_t BIG = (size_t)13824 * 4096 * 2;   // 113,246,208 B
    USH* P1 = (USH*)take(BIG);          // X, then K (in-place LN)
    USH* P2 = (USH*)take(BIG);          // H1; later overlaid: scores fp32 + probs bf16
    USH* P3 = (USH*)take(BIG);          // refreshed
    float* tg  = (float*)take(4096 * 4);
    float* yv  = (float*)take(24 * 4096 * 4);
    float* cst = (float*)take(4096 * 4);
    float* sv  = (float*)take(1024 * 4);
    float* ctx = (float*)take(24 * 4096 * 4);
    USH* textb = (USH*)take((size_t)128 * 4096 * 2);
    USH* Qb   = (USH*)take((size_t)128 * 4096 * 2);
    USH* attb = (USH*)take((size_t)128 * 4096 * 2);
    USH* opre = (USH*)take((size_t)128 * 4096 * 2);
    float* scores = (float*)P2;                                   // 56,623,104 B
    USH* probs = (USH*)((char*)P2 + (size_t)8 * 128 * 13824 * 4); // + 28,311,552 B
    (void)ws_size; (void)in_sizes; (void)n_in; (void)out_size;

    // ---- 1. means + zero cell state + text->bf16 ----
    means_k<<<dim3(16, 26), 256, 0, stream>>>(text, feats, tg, yv, cst);
    f32_to_bf16<<<256, 256, 0, stream>>>(text, textb);

    // ---- 2. DSU recurrence (sequential over 24 layers) ----
    for (int l = 0; l < 24; l++) {
        dsu_s1<<<1024, 256, 0, stream>>>(W1w, W1b, cst, yv + (size_t)l * 4096, tg, sv);
        dsu_s2<<<4096, 256, 0, stream>>>(Wcw, Wcb, Wiw, Wib, Wfw, Wfb, bc, bi, bfv,
                                         sv, cst, ctx + (size_t)l * 4096);
    }

    // ---- 3. spatial gate ----
    make_x<<<27648, 256, 0, stream>>>(feats, ctx, P1);
    gemm_bt<EPI_GELU, true><<<dim3(32, 108, 1), 256, 0, stream>>>(
        P1, 4096, 0, g1w, 4096, 0, P2, 4096, 0, g1b, nullptr, 1.f, 4096);
    gemm_bt<EPI_GATE, true><<<dim3(32, 108, 1), 256, 0, stream>>>(
        P2, 4096, 0, g2w, 4096, 0, P3, 4096, 0, g2b, feats, 1.f, 4096);

    // ---- 4. K = LN(refreshed @ Wk^T + b) ----
    gemm_bt<EPI_PLAIN, true><<<dim3(32, 108, 1), 256, 0, stream>>>(
        P3, 4096, 0, Wkw, 4096, 0, P1, 4096, 0, Wkb, nullptr, 1.f, 4096);
    ln_rows<false><<<13824, 256, 0, stream>>>(P1, P1, kng, knb);

    // ---- 5. Q = LN(text @ Wq^T + b) ----
    gemm_bt<EPI_PLAIN, true><<<dim3(32, 1, 1), 256, 0, stream>>>(
        textb, 4096, 0, Wqw, 4096, 0, Qb, 4096, 0, Wqb, nullptr, 1.f, 4096);
    ln_rows<false><<<128, 256, 0, stream>>>(Qb, Qb, qng, qnb);

    // ---- 6. scores = Q K^T / sqrt(512*24), per head ----
    const float alpha = 0.00902109753f;  // 1/sqrt(512*24)
    gemm_bt<EPI_SCORES, false><<<dim3(108, 1, 8), 256, 0, stream>>>(
        Qb, 4096, 512, P1, 4096, 512, scores, 13824, (long long)128 * 13824,
        nullptr, nullptr, alpha, 512);

    // ---- 7. softmax + PV ----
    softmax_rows<<<1024, 256, 0, stream>>>(scores, probs);
    pv_kernel<<<dim3(8, 4, 8), 256, 0, stream>>>(probs, P3, attb);

    // ---- 8. out = LN(att @ Wo^T + b), fp32 out ----
    gemm_bt<EPI_PLAIN, true><<<dim3(32, 1, 1), 256, 0, stream>>>(
        attb, 4096, 0, Wow, 4096, 0, opre, 4096, 0, Wob, nullptr, 1.f, 4096);
    ln_rows<true><<<128, 256, 0, stream>>>(opre, (float*)d_out, ong, onb);
}